// Round 14
// baseline (862.338 us; speedup 1.0000x reference)
//
#include <hip/hip_runtime.h>
#include <hip/hip_bf16.h>

typedef float f32x4 __attribute__((ext_vector_type(4)));
typedef short bf16x8 __attribute__((ext_vector_type(8)));
typedef short bf16x4 __attribute__((ext_vector_type(4)));
typedef unsigned short u16;

constexpr int T_TOK = 8192;
constexpr int KDIM  = 4096;
constexpr int NDIM  = 4096;
constexpr int NE    = 8;

constexpr long long TA = (long long)T_TOK * KDIM;
constexpr long long TB = (long long)NE * NDIM * KDIM;

__device__ __forceinline__ u16 f2bf(float f) {
  unsigned u = __builtin_bit_cast(unsigned, f);
  u += 0x7FFFu + ((u >> 16) & 1u);
  return (u16)(u >> 16);
}

// ---------------- pass 1: fp32 -> bf16 convert, A ONLY -----------------------
__global__ __launch_bounds__(256)
void cvt_bf16_A(const float* __restrict__ A, u16* __restrict__ oA) {
  const long long nv = TA >> 3;
  const long long stride = (long long)gridDim.x * blockDim.x;
  for (long long i = (long long)blockIdx.x * blockDim.x + threadIdx.x; i < nv; i += stride) {
    const long long e = i << 3;
    f32x4 v0 = ((const f32x4*)(A + e))[0];
    f32x4 v1 = ((const f32x4*)(A + e))[1];
    bf16x8 p;
    #pragma unroll
    for (int j = 0; j < 4; ++j) p[j]     = (short)f2bf(v0[j]);
    #pragma unroll
    for (int j = 0; j < 4; ++j) p[4 + j] = (short)f2bf(v1[j]);
    *(bf16x8*)(oA + e) = p;
  }
}

// ---------------- shared helpers ---------------------------------------------
__device__ __forceinline__ void gload16(const u16* g, const u16* l) {
  __builtin_amdgcn_global_load_lds(
      (const __attribute__((address_space(1))) void*)g,
      (__attribute__((address_space(3))) void*)l, 16, 0, 0);
}

constexpr int BM2 = 256, BN2 = 256, BK2 = 64;
constexpr int NKT2 = KDIM / BK2;          // 64 k-tiles
constexpr int NTN2 = NDIM / BN2;          // 16 n-tiles
constexpr int MT2  = T_TOK / BM2 + NE;    // 40 worst-case m-tiles
constexpr int NWG_TOT = MT2 * NTN2;       // 640 worst-case tiles
constexpr int NWG_L1  = 512;              // full-tile blocks (>= 512 tiles exist)
constexpr int NWG_ALL = NWG_L1 + (NWG_TOT - NWG_L1) * 2;   // 768 blocks
constexpr int ASZ  = BM2 * BK2;           // 16384 elems per B buffer (256x64)
constexpr int HSZ  = ASZ / 2;             // 8192 elems (128-row half)

__device__ __forceinline__ bool decode_tile(const int* segp, int mt,
                                            int& e, int& segs, int& sege, int& mloc) {
  e = -1;
  int acc0 = 0, sp = segp[0];
  #pragma unroll
  for (int i = 0; i < NE; ++i) {
    int sn = segp[i + 1];
    int nti = (sn - sp + BM2 - 1) / BM2;
    if (e < 0 && mt < acc0 + nti) { e = i; mloc = mt - acc0; segs = sp; sege = sn; }
    acc0 += nti; sp = sn;
  }
  return e >= 0;
}

// ---------------- merged GEMM: A bf16 via gload_lds, B fp32 reg-staged -------
__global__ __launch_bounds__(512, 2)
void gg_merged(const u16* __restrict__ Abf, const float* __restrict__ Bf,
               float* __restrict__ C, const int* __restrict__ segp,
               const int* __restrict__ widx)
{
  extern __shared__ u16 sm[];

  const int tid = threadIdx.x, lane = tid & 63, wid = tid >> 6;
  const int bid0 = (int)blockIdx.x;

  if (bid0 < NWG_L1) {
    // ================= FULL PATH (256^2, tiles [0,512)) ======================
    u16* sA = sm;               // A: [2 buf][2 half][8192]
    u16* sB = sm + 2 * ASZ;     // B: [2 buf][256 rows][64]  (linear, swizzled)

    int bid = (bid0 & 7) * (NWG_L1 / 8) + (bid0 >> 3);
    const int nt = bid % NTN2;
    const int mt = bid / NTN2;

    int e, segs, sege, mloc;
    if (!decode_tile(segp, mt, e, segs, sege, mloc)) return;

    const int row_base = segs + mloc * BM2;
    const int col_base = nt * BN2;
    const float* __restrict__ W = Bf + (long long)widx[e] * ((long long)NDIM * KDIM);

    const int wr = wid >> 2, wc = wid & 3;

    // ---- A staging (unchanged r7): linear LDS dest, inverse-swizzled src ----
    const int sg = (((lane & 7) ^ (lane >> 3)) << 3);
    const int rr = wid * 8 + (lane >> 3);
    int oA[2][2];
    #pragma unroll
    for (int h = 0; h < 2; ++h)
      #pragma unroll
      for (int i = 0; i < 2; ++i)
        oA[h][i] = min(row_base + h * 128 + i * 64 + rr, T_TOK - 1) * KDIM + sg;

    // ---- B fp32 reg staging: instr j covers rows wid*32+j*4 .. +3 -----------
    // lane -> row wid*32 + j*4 + (lane>>4), k-chunk (lane&15)*4 (4 fp32,
    // 16B, fully coalesced 1KB/instr). cvt -> bf16x4, ds_write_b64 at
    // granule g = (chunk>>1) ^ (row&7), half (chunk&1). Zero write conflict.
    const int brow_l = (lane >> 4);        // row offset within 4-row group
    const int bchunk = lane & 15;          // 4-fp32 chunk within 64-k row
    f32x4 breg[8];
    auto BISSUE = [&](int t) __attribute__((always_inline)) {
      #pragma unroll
      for (int j = 0; j < 8; ++j) {
        const int r = wid * 32 + j * 4 + brow_l;
        breg[j] = *(const f32x4*)(W + (long long)(col_base + r) * KDIM + t * BK2 + bchunk * 4);
      }
    };
    auto BCVT = [&](int bbuf) __attribute__((always_inline)) {
      #pragma unroll
      for (int j = 0; j < 8; ++j) {
        const int r = wid * 32 + j * 4 + brow_l;
        bf16x4 p;
        #pragma unroll
        for (int k = 0; k < 4; ++k) p[k] = (short)f2bf(breg[j][k]);
        const int g = (bchunk >> 1) ^ (r & 7);
        *(bf16x4*)(sB + bbuf * ASZ + r * 64 + g * 8 + (bchunk & 1) * 4) = p;
      }
    };

    // ---- fragment reads (unchanged r7; B rows linear 256x64, key row&7) -----
    const int g0  = (lane >> 4) ^ (lane & 7);
    const int g1  = g0 ^ 4;
    const int rA0 = (wr * 64 + (lane & 15)) * BK2 + g0 * 8;
    const int rA1 = (wr * 64 + (lane & 15)) * BK2 + g1 * 8;
    const int rB0 = (wc * 32 + (lane & 15)) * BK2 + g0 * 8;
    const int rB1 = (wc * 32 + (lane & 15)) * BK2 + g1 * 8;

    f32x4 acc[8][4];
    #pragma unroll
    for (int m = 0; m < 8; ++m)
      #pragma unroll
      for (int n = 0; n < 4; ++n)
        acc[m][n] = (f32x4){0.f, 0.f, 0.f, 0.f};

    bf16x8 aF[4][2], bF0[2][2], bF1[2][2];

    auto STGA = [&](int bbuf, int h, int t) __attribute__((always_inline)) {
      gload16(Abf + oA[h][0] + t * BK2, sA + bbuf * ASZ + h * HSZ + wid * 512);
      gload16(Abf + oA[h][1] + t * BK2, sA + bbuf * ASZ + h * HSZ + 4096 + wid * 512);
    };
    auto LDA = [&](int bbuf, int mh) __attribute__((always_inline)) {
      #pragma unroll
      for (int j = 0; j < 4; ++j) {
        const u16* p = sA + bbuf * ASZ + mh * HSZ + j * 16 * BK2;
        aF[j][0] = *(const bf16x8*)(p + rA0);
        aF[j][1] = *(const bf16x8*)(p + rA1);
      }
    };
    auto LDB = [&](int bbuf, int nh, bf16x8 (&bF)[2][2]) __attribute__((always_inline)) {
      #pragma unroll
      for (int i = 0; i < 2; ++i) {
        const u16* p = sB + bbuf * ASZ + nh * HSZ + i * 16 * BK2;
        bF[i][0] = *(const bf16x8*)(p + rB0);
        bF[i][1] = *(const bf16x8*)(p + rB1);
      }
    };
    auto MF = [&](int mh, int nh, bf16x8 (&bF)[2][2]) __attribute__((always_inline)) {
      __builtin_amdgcn_s_setprio(1);
      #pragma unroll
      for (int j = 0; j < 4; ++j)
        #pragma unroll
        for (int i = 0; i < 2; ++i) {
          acc[mh * 4 + j][nh * 2 + i] = __builtin_amdgcn_mfma_f32_16x16x32_bf16(
              aF[j][0], bF[i][0], acc[mh * 4 + j][nh * 2 + i], 0, 0, 0);
          acc[mh * 4 + j][nh * 2 + i] = __builtin_amdgcn_mfma_f32_16x16x32_bf16(
              aF[j][1], bF[i][1], acc[mh * 4 + j][nh * 2 + i], 0, 0, 0);
        }
      __builtin_amdgcn_s_setprio(0);
    };

    // prologue: A(0) 4 gloads, Bf32(0) 8 reg-loads, A_lo(1) 2 gloads;
    // vmcnt(2) retires A(0)+Bf32(0), leaves A_lo(1); cvt B(0)->buf0.
    STGA(0, 0, 0); STGA(0, 1, 0);
    BISSUE(0);
    STGA(1, 0, 1);
    asm volatile("s_waitcnt vmcnt(2)" ::: "memory");
    BCVT(0);
    asm volatile("s_waitcnt lgkmcnt(0)" ::: "memory");
    __builtin_amdgcn_s_barrier();

    // Ledger: entering tile t outstanding = A_lo(t+1)x2.
    // p1: +{A_hi(t+1)x2, Bf32(t+1)x8} -> 12. p2: +A_lo(t+2)x2 -> 14;
    // vmcnt(2) retires all of tile t+1's loads; cvt B(t+1)->nb; MFMA;
    // lgkm0 (ds_writes) ; BAR. Tail: t+2>=N -> vmcnt(0); guards on issues/cvt.
    for (int t = 0; t < NKT2; ++t) {
      const int bb = t & 1, nb = bb ^ 1;

      // p1: reads A_lo + B(all); stages A_hi(t+1); issues Bf32(t+1)
      LDA(bb, 0); LDB(bb, 0, bF0); LDB(bb, 1, bF1);
      if (t + 1 < NKT2) { STGA(nb, 1, t + 1); BISSUE(t + 1); }
      MF(0, 0, bF0); MF(0, 1, bF1);
      __builtin_amdgcn_s_barrier();

      // p2: reads A_hi; stages A_lo(t+2); cvt+write B(t+1)
      LDA(bb, 1);
      if (t + 2 < NKT2) STGA(bb, 0, t + 2);
      if (t + 2 < NKT2) {
        asm volatile("s_waitcnt vmcnt(2)" ::: "memory");
      } else {
        asm volatile("s_waitcnt vmcnt(0)" ::: "memory");
      }
      if (t + 1 < NKT2) BCVT(nb);
      MF(1, 0, bF0); MF(1, 1, bF1);
      asm volatile("s_waitcnt lgkmcnt(0)" ::: "memory");
      __builtin_amdgcn_s_barrier();
    }

    #pragma unroll
    for (int m = 0; m < 8; ++m) {
      const int r0 = row_base + (m >> 2) * 128 + wr * 64 + (m & 3) * 16 + ((lane >> 4) << 2);
      #pragma unroll
      for (int j = 0; j < 4; ++j) {
        const int r = r0 + j;
        if (r < sege) {
          float* cp = C + (long long)r * NDIM + col_base + (lane & 15);
          #pragma unroll
          for (int n = 0; n < 4; ++n)
            cp[(n >> 1) * 128 + wc * 32 + (n & 1) * 16] = acc[m][n][j];
        }
      }
    }
  } else {
    // ================= HALF PATH (tiles [512,640) x 2 halves) ================
    u16* sA = sm;                  // [2][8192]  (128 rows x 64)
    u16* sB = sm + 2 * HSZ;        // [2][16384] (256 rows x 64)

    const int b = bid0 - NWG_L1;
    const int swz = (b & 7) * 32 + (b >> 3);
    const int tile = NWG_L1 + (swz >> 1);
    const int mh   = swz & 1;
    const int nt = tile % NTN2;
    const int mt = tile / NTN2;

    int e, segs, sege, mloc;
    if (!decode_tile(segp, mt, e, segs, sege, mloc)) return;

    const int row_base = segs + mloc * BM2 + mh * 128;
    const int col_base = nt * BN2;
    const float* __restrict__ W = Bf + (long long)widx[e] * ((long long)NDIM * KDIM);

    const int wr = wid >> 2, wc = wid & 3;

    const int sg = (((lane & 7) ^ (lane >> 3)) << 3);
    const int rr = wid * 8 + (lane >> 3);
    int oA[2];
    #pragma unroll
    for (int i = 0; i < 2; ++i)
      oA[i] = min(row_base + i * 64 + rr, T_TOK - 1) * KDIM + sg;

    const int brow_l = (lane >> 4);
    const int bchunk = lane & 15;
    f32x4 breg[8];
    auto BISSUE = [&](int t) __attribute__((always_inline)) {
      #pragma unroll
      for (int j = 0; j < 8; ++j) {
        const int r = wid * 32 + j * 4 + brow_l;
        breg[j] = *(const f32x4*)(W + (long long)(col_base + r) * KDIM + t * BK2 + bchunk * 4);
      }
    };
    auto BCVT = [&](int bbuf) __attribute__((always_inline)) {
      #pragma unroll
      for (int j = 0; j < 8; ++j) {
        const int r = wid * 32 + j * 4 + brow_l;
        bf16x4 p;
        #pragma unroll
        for (int k = 0; k < 4; ++k) p[k] = (short)f2bf(breg[j][k]);
        const int g = (bchunk >> 1) ^ (r & 7);
        *(bf16x4*)(sB + bbuf * ASZ + r * 64 + g * 8 + (bchunk & 1) * 4) = p;
      }
    };

    const int g0  = (lane >> 4) ^ (lane & 7);
    const int g1  = g0 ^ 4;
    const int rA0 = (wr * 64 + (lane & 15)) * BK2 + g0 * 8;
    const int rA1 = (wr * 64 + (lane & 15)) * BK2 + g1 * 8;
    const int rB0 = (wc * 64 + (lane & 15)) * BK2 + g0 * 8;
    const int rB1 = (wc * 64 + (lane & 15)) * BK2 + g1 * 8;

    f32x4 acc[4][4];
    #pragma unroll
    for (int m = 0; m < 4; ++m)
      #pragma unroll
      for (int n = 0; n < 4; ++n)
        acc[m][n] = (f32x4){0.f, 0.f, 0.f, 0.f};

    auto STAGE_A = [&](int bbuf, int t) __attribute__((always_inline)) {
      gload16(Abf + oA[0] + t * BK2, sA + bbuf * HSZ + wid * 512);
      gload16(Abf + oA[1] + t * BK2, sA + bbuf * HSZ + 4096 + wid * 512);
    };

    // prologue: A(0)2, Bf32(0)8, A(1)2; vmcnt(2); cvt B(0)->buf0
    STAGE_A(0, 0);
    BISSUE(0);
    STAGE_A(1, 1);
    asm volatile("s_waitcnt vmcnt(2)" ::: "memory");
    BCVT(0);
    asm volatile("s_waitcnt lgkmcnt(0)" ::: "memory");
    __builtin_amdgcn_s_barrier();

    // Ledger: entering t outstanding = A(t+1)x2; +Bf32(t+1)8 +A(t+2)2 -> 12;
    // vmcnt(2) retires t+1 set; cvt B(t+1)->nb; MFMA; lgkm0; BAR.
    for (int t = 0; t < NKT2; ++t) {
      const int bb = t & 1, nb = bb ^ 1;

      bf16x8 aF[4][2], bF[4][2];
      #pragma unroll
      for (int m = 0; m < 4; ++m) {
        const u16* p = sA + bb * HSZ + m * 16 * BK2;
        aF[m][0] = *(const bf16x8*)(p + rA0);
        aF[m][1] = *(const bf16x8*)(p + rA1);
      }
      #pragma unroll
      for (int n = 0; n < 4; ++n) {
        const u16* p = sB + bb * ASZ + n * 16 * BK2;
        bF[n][0] = *(const bf16x8*)(p + rB0);
        bF[n][1] = *(const bf16x8*)(p + rB1);
      }
      if (t + 1 < NKT2) BISSUE(t + 1);

      asm volatile("s_waitcnt lgkmcnt(0)" ::: "memory");
      __builtin_amdgcn_s_barrier();

      if (t + 2 < NKT2) STAGE_A(bb, t + 2);
      if (t + 2 < NKT2) {
        asm volatile("s_waitcnt vmcnt(2)" ::: "memory");
      } else {
        asm volatile("s_waitcnt vmcnt(0)" ::: "memory");
      }
      if (t + 1 < NKT2) BCVT(nb);

      __builtin_amdgcn_s_setprio(1);
      #pragma unroll
      for (int m = 0; m < 4; ++m)
        #pragma unroll
        for (int n = 0; n < 4; ++n) {
          acc[m][n] = __builtin_amdgcn_mfma_f32_16x16x32_bf16(aF[m][0], bF[n][0], acc[m][n], 0, 0, 0);
          acc[m][n] = __builtin_amdgcn_mfma_f32_16x16x32_bf16(aF[m][1], bF[n][1], acc[m][n], 0, 0, 0);
        }
      __builtin_amdgcn_s_setprio(0);

      asm volatile("s_waitcnt lgkmcnt(0)" ::: "memory");
      __builtin_amdgcn_s_barrier();
    }

    #pragma unroll
    for (int m = 0; m < 4; ++m) {
      const int r0 = row_base + wr * 64 + m * 16 + ((lane >> 4) << 2);
      #pragma unroll
      for (int j = 0; j < 4; ++j) {
        const int r = r0 + j;
        if (r < sege) {
          float* cp = C + (long long)r * NDIM + col_base + wc * 64 + (lane & 15);
          #pragma unroll
          for (int n = 0; n < 4; ++n)
            cp[n * 16] = acc[m][n][j];
        }
      }
    }
  }
}

// ---------------- fallback (round-1 fused convert+GEMM) ----------------------
constexpr int BM = 128, BN = 128, BK = 32;
constexpr int LDKF = BK + 8;
constexpr int NTN = NDIM / BN;
constexpr int MT_MAX = T_TOK / BM + NE;
constexpr int NKT = KDIM / BK;
constexpr int NWG = MT_MAX * NTN;

__global__ __launch_bounds__(256, 2)
void grouped_gemm_fused(const float* __restrict__ A, const float* __restrict__ B,
                        float* __restrict__ C, const int* __restrict__ segp,
                        const int* __restrict__ widx)
{
  __shared__ u16 lA[2][BM][LDKF];
  __shared__ u16 lB[2][BN][LDKF];

  const int nt = blockIdx.x % NTN;
  const int mt = blockIdx.x / NTN;

  int e = -1, segs = 0, sege = 0, mloc = 0;
  {
    int acc0 = 0, sp = segp[0];
    #pragma unroll
    for (int i = 0; i < NE; ++i) {
      int sn = segp[i + 1];
      int nti = (sn - sp + BM - 1) / BM;
      if (e < 0 && mt < acc0 + nti) { e = i; mloc = mt - acc0; segs = sp; sege = sn; }
      acc0 += nti; sp = sn;
    }
  }
  if (e < 0) return;

  const int row_base = segs + mloc * BM;
  const int col_base = nt * BN;
  const float* __restrict__ W = B + (long long)widx[e] * NDIM * KDIM;

  const int tid  = threadIdx.x;
  const int lane = tid & 63;
  const int wid  = tid >> 6;
  const int wr   = wid >> 1;
  const int wc   = wid & 1;

  const int srow = tid >> 1;
  const int scol = (tid & 1) << 4;
  const int arow = min(row_base + srow, T_TOK - 1);
  const float* __restrict__ aptr = A + (long long)arow * KDIM + scol;
  const float* __restrict__ bptr = W + (long long)(col_base + srow) * KDIM + scol;

  f32x4 sa[4], sb[4];
  f32x4 acc[4][4];
  #pragma unroll
  for (int m = 0; m < 4; ++m)
    #pragma unroll
    for (int n = 0; n < 4; ++n)
      acc[m][n] = (f32x4){0.f, 0.f, 0.f, 0.f};

  const int frow = lane & 15;
  const int fk   = (lane >> 4) << 3;

  auto load_tiles = [&](int kt) {
    const float* ap = aptr + kt * BK;
    const float* bp = bptr + kt * BK;
    #pragma unroll
    for (int i = 0; i < 4; ++i) sa[i] = *(const f32x4*)(ap + i * 4);
    #pragma unroll
    for (int i = 0; i < 4; ++i) sb[i] = *(const f32x4*)(bp + i * 4);
  };
  auto conv_write = [&](int buf) {
    u16* wa = &lA[buf][srow][scol];
    u16* wb = &lB[buf][srow][scol];
    bf16x8 p;
    #pragma unroll
    for (int j = 0; j < 8; ++j) p[j] = (short)f2bf(sa[j >> 2][j & 3]);
    *(bf16x8*)(wa) = p;
    #pragma unroll
    for (int j = 0; j < 8; ++j) p[j] = (short)f2bf(sa[2 + (j >> 2)][j & 3]);
    *(bf16x8*)(wa + 8) = p;
    #pragma unroll
    for (int j = 0; j < 8; ++j) p[j] = (short)f2bf(sb[j >> 2][j & 3]);
    *(bf16x8*)(wb) = p;
    #pragma unroll
    for (int j = 0; j < 8; ++j) p[j] = (short)f2bf(sb[2 + (j >> 2)][j & 3]);
    *(bf16x8*)(wb + 8) = p;
  };

  load_tiles(0);
  conv_write(0);
  __syncthreads();

  int cur = 0;
  for (int kt = 0; kt < NKT; ++kt) {
    const bool more = (kt + 1 < NKT);
    if (more) load_tiles(kt + 1);

    bf16x8 af[4], bfr[4];
    #pragma unroll
    for (int m = 0; m < 4; ++m)
      af[m] = *(const bf16x8*)&lA[cur][wr * 64 + m * 16 + frow][fk];
    #pragma unroll
    for (int n = 0; n < 4; ++n)
      bfr[n] = *(const bf16x8*)&lB[cur][wc * 64 + n * 16 + frow][fk];

    if (more) conv_write(cur ^ 1);

    #pragma unroll
    for (int m = 0; m < 4; ++m)
      #pragma unroll
      for (int n = 0; n < 4; ++n)
        acc[m][n] = __builtin_amdgcn_mfma_f32_16x16x32_bf16(af[m], bfr[n], acc[m][n], 0, 0, 0);

    __syncthreads();
    cur ^= 1;
  }

  const int crow0 = row_base + wr * 64;
  const int ccol  = col_base + wc * 64 + (lane & 15);
  const int rsub  = (lane >> 4) << 2;
  #pragma unroll
  for (int m = 0; m < 4; ++m) {
    #pragma unroll
    for (int j = 0; j < 4; ++j) {
      const int r = crow0 + m * 16 + rsub + j;
      if (r < sege) {
        #pragma unroll
        for (int n = 0; n < 4; ++n)
          C[(long long)r * NDIM + ccol + n * 16] = acc[m][n][j];
      }
    }
  }
}

extern "C" void kernel_launch(void* const* d_in, const int* in_sizes, int n_in,
                              void* d_out, int out_size, void* d_ws, size_t ws_size,
                              hipStream_t stream) {
  const float* A   = (const float*)d_in[0];
  const float* B   = (const float*)d_in[1];
  const int* segp  = (const int*)d_in[3];
  const int* widx  = (const int*)d_in[4];
  float* C = (float*)d_out;

  const size_t need = (size_t)TA * sizeof(u16);   // 64 MB (A only)
  if (ws_size >= need) {
    u16* oA = (u16*)d_ws;
    cvt_bf16_A<<<dim3(1024), dim3(256), 0, stream>>>(A, oA);
    (void)hipFuncSetAttribute((const void*)gg_merged,
                              hipFuncAttributeMaxDynamicSharedMemorySize,
                              2 * 2 * ASZ * (int)sizeof(u16));           // 128 KB
    gg_merged<<<dim3(NWG_ALL), dim3(512), 2 * 2 * ASZ * sizeof(u16), stream>>>(
        oA, B, C, segp, widx);
  } else {
    grouped_gemm_fused<<<dim3(NWG), dim3(256), 0, stream>>>(A, B, C, segp, widx);
  }
}

// Round 15
// 472.792 us; speedup vs baseline: 1.8239x; 1.8239x over previous
//
#include <hip/hip_runtime.h>
#include <hip/hip_bf16.h>

typedef float f32x4 __attribute__((ext_vector_type(4)));
typedef short bf16x8 __attribute__((ext_vector_type(8)));
typedef unsigned short u16;

constexpr int T_TOK = 8192;
constexpr int KDIM  = 4096;
constexpr int NDIM  = 4096;
constexpr int NE    = 8;

constexpr long long TA = (long long)T_TOK * KDIM;
constexpr long long TB = (long long)NE * NDIM * KDIM;

__device__ __forceinline__ u16 f2bf(float f) {
  unsigned u = __builtin_bit_cast(unsigned, f);
  u += 0x7FFFu + ((u >> 16) & 1u);
  return (u16)(u >> 16);
}

// ---------------- pass 1: fp32 -> bf16 streaming convert ---------------------
__global__ __launch_bounds__(256)
void cvt_bf16(const float* __restrict__ A, const float* __restrict__ B,
              u16* __restrict__ oA, u16* __restrict__ oB) {
  const long long nv = (TA + TB) >> 3;
  const long long stride = (long long)gridDim.x * blockDim.x;
  for (long long i = (long long)blockIdx.x * blockDim.x + threadIdx.x; i < nv; i += stride) {
    const long long e = i << 3;
    const float* s;
    u16* d;
    if (e < TA) { s = A + e;        d = oA + e; }
    else        { s = B + (e - TA); d = oB + (e - TA); }
    f32x4 v0 = ((const f32x4*)s)[0];
    f32x4 v1 = ((const f32x4*)s)[1];
    bf16x8 p;
    #pragma unroll
    for (int j = 0; j < 4; ++j) p[j]     = (short)f2bf(v0[j]);
    #pragma unroll
    for (int j = 0; j < 4; ++j) p[4 + j] = (short)f2bf(v1[j]);
    *(bf16x8*)d = p;
  }
}

// ---------------- shared helpers ---------------------------------------------
__device__ __forceinline__ void gload16(const u16* g, const u16* l) {
  __builtin_amdgcn_global_load_lds(
      (const __attribute__((address_space(1))) void*)g,
      (__attribute__((address_space(3))) void*)l, 16, 0, 0);
}

constexpr int BM2 = 256, BN2 = 256, BK2 = 64;
constexpr int NKT2 = KDIM / BK2;          // 64 k-tiles
constexpr int NTN2 = NDIM / BN2;          // 16 n-tiles
constexpr int MT2  = T_TOK / BM2 + NE;    // 40 worst-case m-tiles
constexpr int NWG_TOT = MT2 * NTN2;       // 640 worst-case tiles
constexpr int NWG_L1  = 512;              // full-tile blocks (always >= 512 tiles exist)
constexpr int NWG_ALL = NWG_L1 + (NWG_TOT - NWG_L1) * 2;   // 768 blocks
constexpr int ASZ  = BM2 * BK2;           // 16384 elems per buffer per operand
constexpr int HSZ  = ASZ / 2;             // 8192 elems (128-row half)

// expert decode shared by both paths (256-row m-tiles)
__device__ __forceinline__ bool decode_tile(const int* segp, int mt,
                                            int& e, int& segs, int& sege, int& mloc) {
  e = -1;
  int acc0 = 0, sp = segp[0];
  #pragma unroll
  for (int i = 0; i < NE; ++i) {
    int sn = segp[i + 1];
    int nti = (sn - sp + BM2 - 1) / BM2;
    if (e < 0 && mt < acc0 + nti) { e = i; mloc = mt - acc0; segs = sp; sege = sn; }
    acc0 += nti; sp = sn;
  }
  return e >= 0;
}

// ---------------- merged GEMM: full path (tiles [0,512)) + half path ---------
__global__ __launch_bounds__(512, 2)
void gg_merged(const u16* __restrict__ Abf, const u16* __restrict__ Bbf,
               float* __restrict__ C, const int* __restrict__ segp,
               const int* __restrict__ widx)
{
  extern __shared__ u16 sm[];

  const int tid = threadIdx.x, lane = tid & 63, wid = tid >> 6;
  const int bid0 = (int)blockIdx.x;

  if (bid0 < NWG_L1) {
    // ================= FULL PATH (r7 kernel verbatim, tiles [0,512)) =========
    u16* sA = sm;               // [2][2][8192]
    u16* sB = sm + 2 * ASZ;

    int bid = (bid0 & 7) * (NWG_L1 / 8) + (bid0 >> 3);   // bijective over [0,512)
    const int nt = bid % NTN2;
    const int mt = bid / NTN2;

    int e, segs, sege, mloc;
    if (!decode_tile(segp, mt, e, segs, sege, mloc)) return;

    const int row_base = segs + mloc * BM2;
    const int col_base = nt * BN2;
    const u16* __restrict__ W = Bbf + (long long)widx[e] * ((long long)NDIM * KDIM);

    const int wr = wid >> 2, wc = wid & 3;

    const int sg = (((lane & 7) ^ (lane >> 3)) << 3);
    const int rr = wid * 8 + (lane >> 3);
    int oA[2][2], oB[2][2];
    #pragma unroll
    for (int h = 0; h < 2; ++h)
      #pragma unroll
      for (int i = 0; i < 2; ++i) {
        oA[h][i] = min(row_base + h * 128 + i * 64 + rr, T_TOK - 1) * KDIM + sg;
        oB[h][i] = (col_base + h * 128 + i * 64 + rr) * KDIM + sg;
      }

    const int g0  = (lane >> 4) ^ (lane & 7);
    const int g1  = g0 ^ 4;
    const int rA0 = (wr * 64 + (lane & 15)) * BK2 + g0 * 8;
    const int rA1 = (wr * 64 + (lane & 15)) * BK2 + g1 * 8;
    const int rB0 = (wc * 32 + (lane & 15)) * BK2 + g0 * 8;
    const int rB1 = (wc * 32 + (lane & 15)) * BK2 + g1 * 8;

    f32x4 acc[8][4];
    #pragma unroll
    for (int m = 0; m < 8; ++m)
      #pragma unroll
      for (int n = 0; n < 4; ++n)
        acc[m][n] = (f32x4){0.f, 0.f, 0.f, 0.f};

    bf16x8 aF[4][2], bF0[2][2], bF1[2][2];

    auto STGA = [&](int bbuf, int h, int t) __attribute__((always_inline)) {
      gload16(Abf + oA[h][0] + t * BK2, sA + bbuf * ASZ + h * HSZ + wid * 512);
      gload16(Abf + oA[h][1] + t * BK2, sA + bbuf * ASZ + h * HSZ + 4096 + wid * 512);
    };
    auto STGB = [&](int bbuf, int h, int t) __attribute__((always_inline)) {
      gload16(W + oB[h][0] + t * BK2, sB + bbuf * ASZ + h * HSZ + wid * 512);
      gload16(W + oB[h][1] + t * BK2, sB + bbuf * ASZ + h * HSZ + 4096 + wid * 512);
    };
    auto LDA = [&](int bbuf, int mh) __attribute__((always_inline)) {
      #pragma unroll
      for (int j = 0; j < 4; ++j) {
        const u16* p = sA + bbuf * ASZ + mh * HSZ + j * 16 * BK2;
        aF[j][0] = *(const bf16x8*)(p + rA0);
        aF[j][1] = *(const bf16x8*)(p + rA1);
      }
    };
    auto LDB = [&](int bbuf, int nh, bf16x8 (&bF)[2][2]) __attribute__((always_inline)) {
      #pragma unroll
      for (int i = 0; i < 2; ++i) {
        const u16* p = sB + bbuf * ASZ + nh * HSZ + i * 16 * BK2;
        bF[i][0] = *(const bf16x8*)(p + rB0);
        bF[i][1] = *(const bf16x8*)(p + rB1);
      }
    };
    auto MF = [&](int mh, int nh, bf16x8 (&bF)[2][2]) __attribute__((always_inline)) {
      __builtin_amdgcn_s_setprio(1);
      #pragma unroll
      for (int j = 0; j < 4; ++j)
        #pragma unroll
        for (int i = 0; i < 2; ++i) {
          acc[mh * 4 + j][nh * 2 + i] = __builtin_amdgcn_mfma_f32_16x16x32_bf16(
              aF[j][0], bF[i][0], acc[mh * 4 + j][nh * 2 + i], 0, 0, 0);
          acc[mh * 4 + j][nh * 2 + i] = __builtin_amdgcn_mfma_f32_16x16x32_bf16(
              aF[j][1], bF[i][1], acc[mh * 4 + j][nh * 2 + i], 0, 0, 0);
        }
      __builtin_amdgcn_s_setprio(0);
    };

    STGA(0, 0, 0); STGB(0, 0, 0); STGA(0, 1, 0); STGB(0, 1, 0);
    STGA(1, 0, 1); STGB(1, 0, 1);
    asm volatile("s_waitcnt vmcnt(4)" ::: "memory");
    __builtin_amdgcn_s_barrier();

    // r7 ledger (proven): in flight at tile start = lo(t+1) [4]; p1 stages
    // hi(t+1), p2 stages lo(t+2); vmcnt(4) retires tile t+1. Tail: vmcnt(0).
    for (int t = 0; t < NKT2; ++t) {
      const int bb = t & 1, nb = bb ^ 1;

      LDA(bb, 0); LDB(bb, 0, bF0); LDB(bb, 1, bF1);
      if (t + 1 < NKT2) { STGA(nb, 1, t + 1); STGB(nb, 1, t + 1); }
      MF(0, 0, bF0); MF(0, 1, bF1);
      __builtin_amdgcn_s_barrier();

      LDA(bb, 1);
      if (t + 2 < NKT2) { STGA(bb, 0, t + 2); STGB(bb, 0, t + 2); }
      MF(1, 0, bF0); MF(1, 1, bF1);
      if (t + 2 < NKT2) {
        asm volatile("s_waitcnt vmcnt(4)" ::: "memory");
      } else {
        asm volatile("s_waitcnt vmcnt(0)" ::: "memory");
      }
      __builtin_amdgcn_s_barrier();
    }

    #pragma unroll
    for (int m = 0; m < 8; ++m) {
      const int r0 = row_base + (m >> 2) * 128 + wr * 64 + (m & 3) * 16 + ((lane >> 4) << 2);
      #pragma unroll
      for (int j = 0; j < 4; ++j) {
        const int r = r0 + j;
        if (r < sege) {
          float* cp = C + (long long)r * NDIM + col_base + (lane & 15);
          #pragma unroll
          for (int n = 0; n < 4; ++n)
            cp[(n >> 1) * 128 + wc * 32 + (n & 1) * 16] = acc[m][n][j];
        }
      }
    }
  } else {
    // ================= HALF PATH (tiles [512,640) x 2 halves) ================
    u16* sA = sm;                  // [2][8192]  (128 rows x 64)
    u16* sB = sm + 2 * HSZ;        // [2][16384] (256 rows x 64)

    const int b = bid0 - NWG_L1;                 // 0..255
    const int swz = (b & 7) * 32 + (b >> 3);     // bijective over [0,256)
    const int tile = NWG_L1 + (swz >> 1);        // 512..639
    const int mh   = swz & 1;
    const int nt = tile % NTN2;
    const int mt = tile / NTN2;

    int e, segs, sege, mloc;
    if (!decode_tile(segp, mt, e, segs, sege, mloc)) return;

    const int row_base = segs + mloc * BM2 + mh * 128;
    const int col_base = nt * BN2;
    const u16* __restrict__ W = Bbf + (long long)widx[e] * ((long long)NDIM * KDIM);

    const int wr = wid >> 2, wc = wid & 3;

    const int sg = (((lane & 7) ^ (lane >> 3)) << 3);
    const int rr = wid * 8 + (lane >> 3);
    int oA[2], oB[4];
    #pragma unroll
    for (int i = 0; i < 2; ++i)
      oA[i] = min(row_base + i * 64 + rr, T_TOK - 1) * KDIM + sg;
    #pragma unroll
    for (int i = 0; i < 4; ++i)
      oB[i] = (col_base + i * 64 + rr) * KDIM + sg;

    const int g0  = (lane >> 4) ^ (lane & 7);
    const int g1  = g0 ^ 4;
    const int rA0 = (wr * 64 + (lane & 15)) * BK2 + g0 * 8;
    const int rA1 = (wr * 64 + (lane & 15)) * BK2 + g1 * 8;
    const int rB0 = (wc * 64 + (lane & 15)) * BK2 + g0 * 8;
    const int rB1 = (wc * 64 + (lane & 15)) * BK2 + g1 * 8;

    f32x4 acc[4][4];
    #pragma unroll
    for (int m = 0; m < 4; ++m)
      #pragma unroll
      for (int n = 0; n < 4; ++n)
        acc[m][n] = (f32x4){0.f, 0.f, 0.f, 0.f};

    auto STAGE = [&](int bbuf, int t) __attribute__((always_inline)) {
      gload16(Abf + oA[0] + t * BK2, sA + bbuf * HSZ + wid * 512);
      gload16(Abf + oA[1] + t * BK2, sA + bbuf * HSZ + 4096 + wid * 512);
      #pragma unroll
      for (int i = 0; i < 4; ++i)
        gload16(W + oB[i] + t * BK2, sB + bbuf * ASZ + i * 4096 + wid * 512);
    };

    STAGE(0, 0); STAGE(1, 1);
    asm volatile("s_waitcnt vmcnt(6)" ::: "memory");
    __builtin_amdgcn_s_barrier();

    // Ledger: at tile start outstanding = t+1 (6/wave); STAGE adds 6 ->
    // vmcnt(6) retires t+1 exactly. Tail (t+2>=NKT2): vmcnt(0).
    for (int t = 0; t < NKT2; ++t) {
      const int bb = t & 1;

      bf16x8 aF[4][2], bF[4][2];
      #pragma unroll
      for (int m = 0; m < 4; ++m) {
        const u16* p = sA + bb * HSZ + m * 16 * BK2;
        aF[m][0] = *(const bf16x8*)(p + rA0);
        aF[m][1] = *(const bf16x8*)(p + rA1);
      }
      #pragma unroll
      for (int n = 0; n < 4; ++n) {
        const u16* p = sB + bb * ASZ + n * 16 * BK2;
        bF[n][0] = *(const bf16x8*)(p + rB0);
        bF[n][1] = *(const bf16x8*)(p + rB1);
      }

      asm volatile("s_waitcnt lgkmcnt(0)" ::: "memory");
      __builtin_amdgcn_s_barrier();

      if (t + 2 < NKT2) STAGE(bb, t + 2);

      __builtin_amdgcn_s_setprio(1);
      #pragma unroll
      for (int m = 0; m < 4; ++m)
        #pragma unroll
        for (int n = 0; n < 4; ++n) {
          acc[m][n] = __builtin_amdgcn_mfma_f32_16x16x32_bf16(aF[m][0], bF[n][0], acc[m][n], 0, 0, 0);
          acc[m][n] = __builtin_amdgcn_mfma_f32_16x16x32_bf16(aF[m][1], bF[n][1], acc[m][n], 0, 0, 0);
        }
      __builtin_amdgcn_s_setprio(0);

      if (t + 2 < NKT2) {
        asm volatile("s_waitcnt vmcnt(6)" ::: "memory");
      } else {
        asm volatile("s_waitcnt vmcnt(0)" ::: "memory");
      }
      __builtin_amdgcn_s_barrier();
    }

    #pragma unroll
    for (int m = 0; m < 4; ++m) {
      const int r0 = row_base + wr * 64 + m * 16 + ((lane >> 4) << 2);
      #pragma unroll
      for (int j = 0; j < 4; ++j) {
        const int r = r0 + j;
        if (r < sege) {
          float* cp = C + (long long)r * NDIM + col_base + wc * 64 + (lane & 15);
          #pragma unroll
          for (int n = 0; n < 4; ++n)
            cp[n * 16] = acc[m][n][j];
        }
      }
    }
  }
}

// ---------------- fallback (round-1 fused convert+GEMM) ----------------------
constexpr int BM = 128, BN = 128, BK = 32;
constexpr int LDKF = BK + 8;
constexpr int NTN = NDIM / BN;
constexpr int MT_MAX = T_TOK / BM + NE;
constexpr int NKT = KDIM / BK;
constexpr int NWG = MT_MAX * NTN;

__global__ __launch_bounds__(256, 2)
void grouped_gemm_fused(const float* __restrict__ A, const float* __restrict__ B,
                        float* __restrict__ C, const int* __restrict__ segp,
                        const int* __restrict__ widx)
{
  __shared__ u16 lA[2][BM][LDKF];
  __shared__ u16 lB[2][BN][LDKF];

  const int nt = blockIdx.x % NTN;
  const int mt = blockIdx.x / NTN;

  int e = -1, segs = 0, sege = 0, mloc = 0;
  {
    int acc0 = 0, sp = segp[0];
    #pragma unroll
    for (int i = 0; i < NE; ++i) {
      int sn = segp[i + 1];
      int nti = (sn - sp + BM - 1) / BM;
      if (e < 0 && mt < acc0 + nti) { e = i; mloc = mt - acc0; segs = sp; sege = sn; }
      acc0 += nti; sp = sn;
    }
  }
  if (e < 0) return;

  const int row_base = segs + mloc * BM;
  const int col_base = nt * BN;
  const float* __restrict__ W = B + (long long)widx[e] * NDIM * KDIM;

  const int tid  = threadIdx.x;
  const int lane = tid & 63;
  const int wid  = tid >> 6;
  const int wr   = wid >> 1;
  const int wc   = wid & 1;

  const int srow = tid >> 1;
  const int scol = (tid & 1) << 4;
  const int arow = min(row_base + srow, T_TOK - 1);
  const float* __restrict__ aptr = A + (long long)arow * KDIM + scol;
  const float* __restrict__ bptr = W + (long long)(col_base + srow) * KDIM + scol;

  f32x4 sa[4], sb[4];
  f32x4 acc[4][4];
  #pragma unroll
  for (int m = 0; m < 4; ++m)
    #pragma unroll
    for (int n = 0; n < 4; ++n)
      acc[m][n] = (f32x4){0.f, 0.f, 0.f, 0.f};

  const int frow = lane & 15;
  const int fk   = (lane >> 4) << 3;

  auto load_tiles = [&](int kt) {
    const float* ap = aptr + kt * BK;
    const float* bp = bptr + kt * BK;
    #pragma unroll
    for (int i = 0; i < 4; ++i) sa[i] = *(const f32x4*)(ap + i * 4);
    #pragma unroll
    for (int i = 0; i < 4; ++i) sb[i] = *(const f32x4*)(bp + i * 4);
  };
  auto conv_write = [&](int buf) {
    u16* wa = &lA[buf][srow][scol];
    u16* wb = &lB[buf][srow][scol];
    bf16x8 p;
    #pragma unroll
    for (int j = 0; j < 8; ++j) p[j] = (short)f2bf(sa[j >> 2][j & 3]);
    *(bf16x8*)(wa) = p;
    #pragma unroll
    for (int j = 0; j < 8; ++j) p[j] = (short)f2bf(sa[2 + (j >> 2)][j & 3]);
    *(bf16x8*)(wa + 8) = p;
    #pragma unroll
    for (int j = 0; j < 8; ++j) p[j] = (short)f2bf(sb[j >> 2][j & 3]);
    *(bf16x8*)(wb) = p;
    #pragma unroll
    for (int j = 0; j < 8; ++j) p[j] = (short)f2bf(sb[2 + (j >> 2)][j & 3]);
    *(bf16x8*)(wb + 8) = p;
  };

  load_tiles(0);
  conv_write(0);
  __syncthreads();

  int cur = 0;
  for (int kt = 0; kt < NKT; ++kt) {
    const bool more = (kt + 1 < NKT);
    if (more) load_tiles(kt + 1);

    bf16x8 af[4], bfr[4];
    #pragma unroll
    for (int m = 0; m < 4; ++m)
      af[m] = *(const bf16x8*)&lA[cur][wr * 64 + m * 16 + frow][fk];
    #pragma unroll
    for (int n = 0; n < 4; ++n)
      bfr[n] = *(const bf16x8*)&lB[cur][wc * 64 + n * 16 + frow][fk];

    if (more) conv_write(cur ^ 1);

    #pragma unroll
    for (int m = 0; m < 4; ++m)
      #pragma unroll
      for (int n = 0; n < 4; ++n)
        acc[m][n] = __builtin_amdgcn_mfma_f32_16x16x32_bf16(af[m], bfr[n], acc[m][n], 0, 0, 0);

    __syncthreads();
    cur ^= 1;
  }

  const int crow0 = row_base + wr * 64;
  const int ccol  = col_base + wc * 64 + (lane & 15);
  const int rsub  = (lane >> 4) << 2;
  #pragma unroll
  for (int m = 0; m < 4; ++m) {
    #pragma unroll
    for (int j = 0; j < 4; ++j) {
      const int r = crow0 + m * 16 + rsub + j;
      if (r < sege) {
        #pragma unroll
        for (int n = 0; n < 4; ++n)
          C[(long long)r * NDIM + ccol + n * 16] = acc[m][n][j];
      }
    }
  }
}

extern "C" void kernel_launch(void* const* d_in, const int* in_sizes, int n_in,
                              void* d_out, int out_size, void* d_ws, size_t ws_size,
                              hipStream_t stream) {
  const float* A   = (const float*)d_in[0];
  const float* B   = (const float*)d_in[1];
  const int* segp  = (const int*)d_in[3];
  const int* widx  = (const int*)d_in[4];
  float* C = (float*)d_out;

  const size_t need = (size_t)(TA + TB) * sizeof(u16);   // 320 MB
  if (ws_size >= need) {
    u16* oA = (u16*)d_ws;
    u16* oB = oA + TA;
    cvt_bf16<<<dim3(2048), dim3(256), 0, stream>>>(A, B, oA, oB);
    (void)hipFuncSetAttribute((const void*)gg_merged,
                              hipFuncAttributeMaxDynamicSharedMemorySize,
                              2 * 2 * ASZ * (int)sizeof(u16));           // 128 KB
    gg_merged<<<dim3(NWG_ALL), dim3(512), 2 * 2 * ASZ * sizeof(u16), stream>>>(
        oA, oB, C, segp, widx);
  } else {
    grouped_gemm_fused<<<dim3(NWG), dim3(256), 0, stream>>>(A, B, C, segp, widx);
  }
}